// Round 2
// baseline (11312.313 us; speedup 1.0000x reference)
//
#include <hip/hip_runtime.h>

#define B_ 2
#define S_ 2048
#define D_ 2048
#define H_ 16
#define NOPE_ 128
#define ROPE_ 64
#define V_ 128
#define C_ 512
#define QK_ 192   // NOPE+ROPE
#define CR_ 576   // C+ROPE
#define BS_ 4096  // B*S

typedef unsigned short ushort_t;

// ---------- bf16 <-> f32 via raw bits ----------
__device__ __forceinline__ float us2f(ushort_t u) {
    unsigned int x = ((unsigned int)u) << 16;
    return __uint_as_float(x);
}
__device__ __forceinline__ ushort_t f2us(float f) {
    unsigned int x = __float_as_uint(f);
    unsigned int r = (x + 0x7fffu + ((x >> 16) & 1u)) >> 16;
    return (ushort_t)r;
}

// ---------- vectorized load/store helpers (4 contiguous elems) ----------
__device__ __forceinline__ void load4(const float* p, float* o) {
    float4 v = *reinterpret_cast<const float4*>(p);
    o[0] = v.x; o[1] = v.y; o[2] = v.z; o[3] = v.w;
}
__device__ __forceinline__ void load4(const ushort_t* p, float* o) {
    ushort4 v = *reinterpret_cast<const ushort4*>(p);
    o[0] = us2f(v.x); o[1] = us2f(v.y); o[2] = us2f(v.z); o[3] = us2f(v.w);
}
__device__ __forceinline__ void store4(float* p, const float* a) {
    float4 v; v.x = a[0]; v.y = a[1]; v.z = a[2]; v.w = a[3];
    *reinterpret_cast<float4*>(p) = v;
}
__device__ __forceinline__ void store4(ushort_t* p, const float* a) {
    ushort4 v; v.x = f2us(a[0]); v.y = f2us(a[1]); v.z = f2us(a[2]); v.w = f2us(a[3]);
    *reinterpret_cast<ushort4*>(p) = v;
}

// ---------- generic tiled GEMM: C[m][n] = sum_k A[m][k] * B(k,n) ----------
// BT=true : B stored (N,K) row-major.  BT=false: B stored (K,N) row-major.
// 64x64 tile, BK=16, 256 threads, 4x4 register blocking, f32 accumulate.
template <typename TA, typename TB, typename TC, bool BT>
__global__ __launch_bounds__(256) void gemm_k(
    const TA* __restrict__ A, int lda, long long strideAz,
    const TB* __restrict__ Bm, int ldb, long long strideBz,
    TC* __restrict__ Cm, int ldc, long long strideCz,
    int M, int N, int K)
{
    __shared__ float sA[16][68];
    __shared__ float sB[16][68];
    const int tid = threadIdx.x;
    const int z = blockIdx.z;
    A  += (long long)z * strideAz;
    Bm += (long long)z * strideBz;
    Cm += (long long)z * strideCz;
    const int n0 = blockIdx.x * 64;
    const int m0 = blockIdx.y * 64;
    const int tx = tid & 15, ty = tid >> 4;
    const int sm  = tid >> 2;         // 0..63
    const int sk4 = (tid & 3) * 4;    // 0,4,8,12
    const int snk = tid >> 4;         // 0..15  (non-BT B)
    const int snn = (tid & 15) * 4;   // 0..60
    float acc[4][4] = {};
    for (int k0 = 0; k0 < K; k0 += 16) {
        {
            float t4[4];
            load4(&A[(long long)(m0 + sm) * lda + k0 + sk4], t4);
            #pragma unroll
            for (int j = 0; j < 4; ++j) sA[sk4 + j][sm] = t4[j];
        }
        if constexpr (BT) {
            float t4[4];
            load4(&Bm[(long long)(n0 + sm) * ldb + k0 + sk4], t4);
            #pragma unroll
            for (int j = 0; j < 4; ++j) sB[sk4 + j][sm] = t4[j];
        } else {
            float t4[4];
            load4(&Bm[(long long)(k0 + snk) * ldb + n0 + snn], t4);
            #pragma unroll
            for (int j = 0; j < 4; ++j) sB[snk][snn + j] = t4[j];
        }
        __syncthreads();
        #pragma unroll
        for (int kk = 0; kk < 16; ++kk) {
            float a[4], b[4];
            #pragma unroll
            for (int i = 0; i < 4; ++i) a[i] = sA[kk][ty * 4 + i];
            #pragma unroll
            for (int j = 0; j < 4; ++j) b[j] = sB[kk][tx * 4 + j];
            #pragma unroll
            for (int i = 0; i < 4; ++i)
                #pragma unroll
                for (int j = 0; j < 4; ++j)
                    acc[i][j] = fmaf(a[i], b[j], acc[i][j]);
        }
        __syncthreads();
    }
    #pragma unroll
    for (int i = 0; i < 4; ++i) {
        store4(&Cm[(long long)(m0 + ty * 4 + i) * ldc + n0 + tx * 4], acc[i]);
    }
}

// ---------- RoPE on q_pe (in place in q buffer, f32) ----------
__global__ __launch_bounds__(256) void rope_q_k(
    float* __restrict__ q, const float* __restrict__ fc, const float* __restrict__ fs)
{
    int id = blockIdx.x * 256 + threadIdx.x;           // BS*H*32 total
    int i  = id & 31;
    int h  = (id >> 5) & 15;
    int bs = id >> 9;
    int s  = bs & (S_ - 1);
    float c  = fc[s * 32 + i];
    float sn = fs[s * 32 + i];
    float* p = q + (long long)bs * (H_ * QK_) + h * QK_ + NOPE_ + 2 * i;
    float tr = p[0], ti = p[1];
    p[0] = tr * c - ti * sn;
    p[1] = tr * sn + ti * c;
}

// ---------- kv post: rmsnorm(c) in place + rope(k_pe) in place ----------
__global__ __launch_bounds__(256) void kvpost_k(
    float* __restrict__ kv, const float* __restrict__ fc, const float* __restrict__ fs)
{
    int bs = blockIdx.x;
    float* row = kv + (long long)bs * CR_;
    int tid = threadIdx.x;
    float v0 = row[tid], v1 = row[tid + 256];
    float ss = v0 * v0 + v1 * v1;
    #pragma unroll
    for (int m = 1; m < 64; m <<= 1) ss += __shfl_xor(ss, m, 64);
    __shared__ float red[4];
    if ((tid & 63) == 0) red[tid >> 6] = ss;
    __syncthreads();
    float tot = red[0] + red[1] + red[2] + red[3];
    float r = rsqrtf(tot * (1.0f / (float)C_) + 1e-6f);
    row[tid] = v0 * r;
    row[tid + 256] = v1 * r;
    if (tid < 32) {
        int s = bs & (S_ - 1);
        float c  = fc[s * 32 + tid];
        float sn = fs[s * 32 + tid];
        float tr = row[C_ + 2 * tid], ti = row[C_ + 2 * tid + 1];
        row[C_ + 2 * tid]     = tr * c - ti * sn;
        row[C_ + 2 * tid + 1] = tr * sn + ti * c;
    }
}

// ---------- flash attention (vector FMA baseline) ----------
// grid: (S/QB, B*H). block 256. QB=16 q rows, TB=32 kv rows per tile.
#define QB 16
#define TB 32
#define KVP 580  // padded LDS pitch in bf16 elems

__global__ __launch_bounds__(256) void attn_k(
    const ushort_t* __restrict__ qabs,  // (BS,H,512) bf16 (internal)
    const float* __restrict__ qf,       // (BS,H,192) f32 (pe at [128:192], roped)
    const float* __restrict__ kv,       // (BS,576) f32: c normalized | k_pe roped
    ushort_t* __restrict__ outc)        // (BS,H,512) bf16 (internal)
{
    __shared__ ushort_t sQ[QB][KVP];
    __shared__ ushort_t sKV[TB][KVP];
    __shared__ float sP[QB][34];
    __shared__ float sFac[QB];
    __shared__ float sL[QB];

    const int tid = threadIdx.x;
    const int bh = blockIdx.y;
    const int b = bh >> 4, h = bh & 15;
    const int s0 = blockIdx.x * QB;

    for (int idx = tid; idx < QB * CR_; idx += 256) {
        int r = idx / CR_, kk = idx % CR_;
        long long bs = (long long)b * S_ + s0 + r;
        ushort_t v;
        if (kk < C_) v = qabs[(bs * H_ + h) * C_ + kk];
        else         v = f2us(qf[(bs * H_ + h) * QK_ + NOPE_ + (kk - C_)]);
        sQ[r][kk] = v;
    }

    const int sr = tid >> 4;        // score row 0..15
    const int st = (tid & 15) * 2;  // score cols st, st+1
    const int cq = tid & 127;       // pv col group: cols cq*4..+3
    const int rh = tid >> 7;        // pv rows rh*8..rh*8+7
    float m_run = -1e30f, l_run = 0.0f;
    float acc[8][4] = {};
    const float scale = 0.0721687836487032f;  // 192^-0.5

    for (int t0 = 0; t0 < S_; t0 += TB) {
        __syncthreads();  // prev PV done (and first iter: sQ staged)
        for (int idx = tid; idx < TB * CR_; idx += 256) {
            int r = idx / CR_, kk = idx % CR_;
            sKV[r][kk] = f2us(kv[((long long)b * S_ + t0 + r) * CR_ + kk]);
        }
        __syncthreads();
        float d0 = 0.f, d1 = 0.f;
        #pragma unroll 8
        for (int kk = 0; kk < CR_; kk += 4) {
            ushort4 qv = *reinterpret_cast<const ushort4*>(&sQ[sr][kk]);
            ushort4 a0 = *reinterpret_cast<const ushort4*>(&sKV[st][kk]);
            ushort4 a1 = *reinterpret_cast<const ushort4*>(&sKV[st + 1][kk]);
            float q0 = us2f(qv.x), q1 = us2f(qv.y), q2 = us2f(qv.z), q3 = us2f(qv.w);
            d0 = fmaf(q0, us2f(a0.x), d0); d0 = fmaf(q1, us2f(a0.y), d0);
            d0 = fmaf(q2, us2f(a0.z), d0); d0 = fmaf(q3, us2f(a0.w), d0);
            d1 = fmaf(q0, us2f(a1.x), d1); d1 = fmaf(q1, us2f(a1.y), d1);
            d1 = fmaf(q2, us2f(a1.z), d1); d1 = fmaf(q3, us2f(a1.w), d1);
        }
        d0 *= scale; d1 *= scale;
        float mx = fmaxf(d0, d1);
        #pragma unroll
        for (int msk = 1; msk < 16; msk <<= 1) mx = fmaxf(mx, __shfl_xor(mx, msk, 64));
        float m_new = fmaxf(m_run, mx);
        float fac = __expf(m_run - m_new);
        float p0 = __expf(d0 - m_new), p1 = __expf(d1 - m_new);
        float ps = p0 + p1;
        #pragma unroll
        for (int msk = 1; msk < 16; msk <<= 1) ps += __shfl_xor(ps, msk, 64);
        l_run = l_run * fac + ps;
        m_run = m_new;
        sP[sr][st] = p0; sP[sr][st + 1] = p1;
        if ((tid & 15) == 0) sFac[sr] = fac;
        __syncthreads();
        #pragma unroll
        for (int i = 0; i < 8; ++i) {
            float f = sFac[rh * 8 + i];
            #pragma unroll
            for (int j = 0; j < 4; ++j) acc[i][j] *= f;
        }
        #pragma unroll 4
        for (int t = 0; t < TB; ++t) {
            ushort4 cv = *reinterpret_cast<const ushort4*>(&sKV[t][cq * 4]);
            float c0 = us2f(cv.x), c1 = us2f(cv.y), c2 = us2f(cv.z), c3 = us2f(cv.w);
            #pragma unroll
            for (int i = 0; i < 8; ++i) {
                float p = sP[rh * 8 + i][t];
                acc[i][0] = fmaf(p, c0, acc[i][0]);
                acc[i][1] = fmaf(p, c1, acc[i][1]);
                acc[i][2] = fmaf(p, c2, acc[i][2]);
                acc[i][3] = fmaf(p, c3, acc[i][3]);
            }
        }
    }
    if ((tid & 15) == 0) sL[sr] = l_run;
    __syncthreads();
    #pragma unroll
    for (int i = 0; i < 8; ++i) {
        float inv = 1.0f / sL[rh * 8 + i];
        long long s = s0 + rh * 8 + i;
        long long base = (((long long)b * S_ + s) * H_ + h) * C_ + cq * 4;
        ushort4 o;
        o.x = f2us(acc[i][0] * inv); o.y = f2us(acc[i][1] * inv);
        o.z = f2us(acc[i][2] * inv); o.w = f2us(acc[i][3] * inv);
        *reinterpret_cast<ushort4*>(&outc[base]) = o;
    }
}

// ---------- workspace layout (bytes) ----------
// qbuf  f32 BS x 3072   @ 0          : 50,331,648
// kvbuf f32 BS x 576    @ 50331648   :  9,437,184
// qabs  bf16 BS x H x 512 @ 59768832 : 67,108,864
// outc  bf16 BS x H x 512 @126877696 : 67,108,864
// aout  f32 BS x 2048   @ 193986560  : 33,554,432
// total 227,540,992

extern "C" void kernel_launch(void* const* d_in, const int* in_sizes, int n_in,
                              void* d_out, int out_size, void* d_ws, size_t ws_size,
                              hipStream_t stream)
{
    if (ws_size < 227540992ULL) return;
    const float* x    = (const float*)d_in[0];
    const float* fc   = (const float*)d_in[1];
    const float* fs   = (const float*)d_in[2];
    const float* wq   = (const float*)d_in[3];
    const float* wkva = (const float*)d_in[4];
    const float* wkvb = (const float*)d_in[5];
    const float* wo   = (const float*)d_in[6];
    float* out = (float*)d_out;

    char* ws = (char*)d_ws;
    float*    qbuf  = (float*)(ws);
    float*    kvbuf = (float*)(ws + 50331648);
    ushort_t* qabs  = (ushort_t*)(ws + 59768832);
    ushort_t* outc  = (ushort_t*)(ws + 126877696);
    float*    aout  = (float*)(ws + 193986560);

    // 1) q = x @ wq^T  (4096x3072, K=2048) -> f32
    gemm_k<float, float, float, true><<<dim3(48, 64, 1), 256, 0, stream>>>(
        x, D_, 0, wq, D_, 0, qbuf, H_ * QK_, 0, BS_, H_ * QK_, D_);
    // 2) kv = x @ wkv_a^T (4096x576, K=2048) -> f32
    gemm_k<float, float, float, true><<<dim3(9, 64, 1), 256, 0, stream>>>(
        x, D_, 0, wkva, D_, 0, kvbuf, CR_, 0, BS_, CR_, D_);
    // 3) rope q_pe in place
    rope_q_k<<<dim3(BS_ * H_ * 32 / 256), 256, 0, stream>>>(qbuf, fc, fs);
    // 4) rmsnorm c + rope k_pe in place
    kvpost_k<<<dim3(BS_), 256, 0, stream>>>(kvbuf, fc, fs);
    // 5) q_abs[h] = q_nope[h] @ w_nope[h]  (z=16: 4096x512, K=128) -> bf16
    gemm_k<float, float, ushort_t, false><<<dim3(8, 64, 16), 256, 0, stream>>>(
        qbuf, H_ * QK_, QK_, wkvb, C_, (long long)(NOPE_ + V_) * C_,
        qabs, H_ * C_, C_, BS_, C_, NOPE_);
    // 6) attention -> outc bf16
    attn_k<<<dim3(S_ / QB, B_ * H_), 256, 0, stream>>>(qabs, qbuf, kvbuf, outc);
    // 7) out[h] = out_c[h] @ w_v[h]^T (z=16: 4096x128, K=512) -> f32
    gemm_k<ushort_t, float, float, true><<<dim3(2, 64, 16), 256, 0, stream>>>(
        outc, H_ * C_, C_, wkvb + (long long)NOPE_ * C_, C_, (long long)(NOPE_ + V_) * C_,
        aout, H_ * V_, V_, BS_, V_, C_);
    // 8) final = aout @ wo^T (4096x2048, K=2048) -> f32 out
    gemm_k<float, float, float, true><<<dim3(32, 64, 1), 256, 0, stream>>>(
        aout, H_ * V_, 0, wo, H_ * V_, 0, out, D_, 0, BS_, D_, H_ * V_);
}

// Round 3
// 2557.387 us; speedup vs baseline: 4.4234x; 4.4234x over previous
//
#include <hip/hip_runtime.h>

#define B_ 2
#define S_ 2048
#define D_ 2048
#define H_ 16
#define NOPE_ 128
#define ROPE_ 64
#define V_ 128
#define C_ 512
#define QK_ 192   // NOPE+ROPE
#define CR_ 576   // C+ROPE
#define BS_ 4096  // B*S

typedef unsigned short ushort_t;
typedef unsigned int uint_t;
typedef __attribute__((ext_vector_type(8))) short bf16x8;
typedef __attribute__((ext_vector_type(4))) float f32x4;

// ---------- bf16 <-> f32 via raw bits ----------
__device__ __forceinline__ float us2f(ushort_t u) {
    unsigned int x = ((unsigned int)u) << 16;
    return __uint_as_float(x);
}
__device__ __forceinline__ ushort_t f2us(float f) {
    unsigned int x = __float_as_uint(f);
    unsigned int r = (x + 0x7fffu + ((x >> 16) & 1u)) >> 16;
    return (ushort_t)r;
}

// ---------- vectorized load/store helpers ----------
__device__ __forceinline__ void load4(const float* p, float* o) {
    float4 v = *reinterpret_cast<const float4*>(p);
    o[0] = v.x; o[1] = v.y; o[2] = v.z; o[3] = v.w;
}
__device__ __forceinline__ void load4(const ushort_t* p, float* o) {
    ushort4 v = *reinterpret_cast<const ushort4*>(p);
    o[0] = us2f(v.x); o[1] = us2f(v.y); o[2] = us2f(v.z); o[3] = us2f(v.w);
}
__device__ __forceinline__ void store4(float* p, const float* a) {
    float4 v; v.x = a[0]; v.y = a[1]; v.z = a[2]; v.w = a[3];
    *reinterpret_cast<float4*>(p) = v;
}
__device__ __forceinline__ void store4(ushort_t* p, const float* a) {
    ushort4 v; v.x = f2us(a[0]); v.y = f2us(a[1]); v.z = f2us(a[2]); v.w = f2us(a[3]);
    *reinterpret_cast<ushort4*>(p) = v;
}

// ---------- generic tiled GEMM (vector FMA; unchanged from r2) ----------
template <typename TA, typename TB, typename TC, bool BT>
__global__ __launch_bounds__(256) void gemm_k(
    const TA* __restrict__ A, int lda, long long strideAz,
    const TB* __restrict__ Bm, int ldb, long long strideBz,
    TC* __restrict__ Cm, int ldc, long long strideCz,
    int M, int N, int K)
{
    __shared__ float sA[16][68];
    __shared__ float sB[16][68];
    const int tid = threadIdx.x;
    const int z = blockIdx.z;
    A  += (long long)z * strideAz;
    Bm += (long long)z * strideBz;
    Cm += (long long)z * strideCz;
    const int n0 = blockIdx.x * 64;
    const int m0 = blockIdx.y * 64;
    const int tx = tid & 15, ty = tid >> 4;
    const int sm  = tid >> 2;
    const int sk4 = (tid & 3) * 4;
    const int snk = tid >> 4;
    const int snn = (tid & 15) * 4;
    float acc[4][4] = {};
    for (int k0 = 0; k0 < K; k0 += 16) {
        {
            float t4[4];
            load4(&A[(long long)(m0 + sm) * lda + k0 + sk4], t4);
            #pragma unroll
            for (int j = 0; j < 4; ++j) sA[sk4 + j][sm] = t4[j];
        }
        if constexpr (BT) {
            float t4[4];
            load4(&Bm[(long long)(n0 + sm) * ldb + k0 + sk4], t4);
            #pragma unroll
            for (int j = 0; j < 4; ++j) sB[sk4 + j][sm] = t4[j];
        } else {
            float t4[4];
            load4(&Bm[(long long)(k0 + snk) * ldb + n0 + snn], t4);
            #pragma unroll
            for (int j = 0; j < 4; ++j) sB[snk][snn + j] = t4[j];
        }
        __syncthreads();
        #pragma unroll
        for (int kk = 0; kk < 16; ++kk) {
            float a[4], b[4];
            #pragma unroll
            for (int i = 0; i < 4; ++i) a[i] = sA[kk][ty * 4 + i];
            #pragma unroll
            for (int j = 0; j < 4; ++j) b[j] = sB[kk][tx * 4 + j];
            #pragma unroll
            for (int i = 0; i < 4; ++i)
                #pragma unroll
                for (int j = 0; j < 4; ++j)
                    acc[i][j] = fmaf(a[i], b[j], acc[i][j]);
        }
        __syncthreads();
    }
    #pragma unroll
    for (int i = 0; i < 4; ++i) {
        store4(&Cm[(long long)(m0 + ty * 4 + i) * ldc + n0 + tx * 4], acc[i]);
    }
}

// ---------- RoPE on q_pe: read qbuf f32, write qcat bf16 pe-part ----------
// qcat layout: [H][BS][576]
__global__ __launch_bounds__(256) void rope_q_k(
    const float* __restrict__ q, ushort_t* __restrict__ qcat,
    const float* __restrict__ fc, const float* __restrict__ fs)
{
    int id = blockIdx.x * 256 + threadIdx.x;           // BS*H*32 total
    int i  = id & 31;
    int h  = (id >> 5) & 15;
    int bs = id >> 9;
    int s  = bs & (S_ - 1);
    float c  = fc[s * 32 + i];
    float sn = fs[s * 32 + i];
    const float* p = q + (long long)bs * (H_ * QK_) + h * QK_ + NOPE_ + 2 * i;
    float tr = p[0], ti = p[1];
    float orr = tr * c - ti * sn;
    float oii = tr * sn + ti * c;
    uint_t wrd = (uint_t)f2us(orr) | ((uint_t)f2us(oii) << 16);
    ((uint_t*)qcat)[((long long)h * BS_ + bs) * 288 + 256 + i] = wrd;
}

// ---------- kv post: rmsnorm(c) + rope(k_pe) -> kvb16 bf16 [BS][576] ----------
__global__ __launch_bounds__(256) void kvpost_k(
    const float* __restrict__ kv, ushort_t* __restrict__ kvb16,
    const float* __restrict__ fc, const float* __restrict__ fs)
{
    int bs = blockIdx.x;
    const float* row = kv + (long long)bs * CR_;
    ushort_t* orow = kvb16 + (long long)bs * CR_;
    int tid = threadIdx.x;
    float v0 = row[tid], v1 = row[tid + 256];
    float ss = v0 * v0 + v1 * v1;
    #pragma unroll
    for (int m = 1; m < 64; m <<= 1) ss += __shfl_xor(ss, m, 64);
    __shared__ float red[4];
    if ((tid & 63) == 0) red[tid >> 6] = ss;
    __syncthreads();
    float tot = red[0] + red[1] + red[2] + red[3];
    float r = rsqrtf(tot * (1.0f / (float)C_) + 1e-6f);
    orow[tid] = f2us(v0 * r);
    orow[tid + 256] = f2us(v1 * r);
    if (tid < 32) {
        int s = bs & (S_ - 1);
        float c  = fc[s * 32 + tid];
        float sn = fs[s * 32 + tid];
        float tr = row[C_ + 2 * tid], ti = row[C_ + 2 * tid + 1];
        orow[C_ + 2 * tid]     = f2us(tr * c - ti * sn);
        orow[C_ + 2 * tid + 1] = f2us(tr * sn + ti * c);
    }
}

// ---------- transpose c-part of kvb16 -> vT16 [B][512][2048] ----------
__global__ __launch_bounds__(256) void vtrans_k(
    const ushort_t* __restrict__ kvb16, ushort_t* __restrict__ vT16)
{
    __shared__ ushort_t st[32][36];
    int b = blockIdx.z;
    int s0 = blockIdx.x * 32, c0 = blockIdx.y * 32;
    int t = threadIdx.x;
    int sl = t >> 3, c4 = (t & 7) * 4;
    ushort4 v = *reinterpret_cast<const ushort4*>(
        kvb16 + ((long long)(b * S_ + s0 + sl)) * CR_ + c0 + c4);
    st[sl][c4] = v.x; st[sl][c4+1] = v.y; st[sl][c4+2] = v.z; st[sl][c4+3] = v.w;
    __syncthreads();
    int cl = t >> 3, s4 = (t & 7) * 4;
    ushort4 o;
    o.x = st[s4][cl]; o.y = st[s4+1][cl]; o.z = st[s4+2][cl]; o.w = st[s4+3][cl];
    *reinterpret_cast<ushort4*>(
        vT16 + ((long long)b * 512 + c0 + cl) * 2048 + s0 + s4) = o;
}

// ---------- MFMA flash attention ----------
// grid (S/64, B*H), 256 threads (4 waves). QB=64 (16 rows/wave), TB=32.
// scores^T = mfma(A=KV, B=Q) -> lane-local softmax; out^T = mfma(A=V^T, B=P^T).
__global__ __launch_bounds__(256, 2) void attn_mfma_k(
    const ushort_t* __restrict__ qcat,   // [H][BS][576] bf16
    const ushort_t* __restrict__ kvb16,  // [BS][576] bf16
    const ushort_t* __restrict__ vT16,   // [B][512][2048] bf16
    ushort_t* __restrict__ outc)         // [BS][H][512] bf16
{
    __shared__ ushort_t sKV[32][584];    // pitch 584: 16B-aligned rows, 2-way banks
    __shared__ ushort_t sVT[512 * 32];   // line-pair chunk-XOR swizzle
    __shared__ ushort_t sP[64][40];      // pitch 40
    __shared__ float sFac[64];
    __shared__ float sL[64];
    __shared__ int sNeedA[4];

    const int tid = threadIdx.x;
    const int w   = tid >> 6;
    const int ln  = tid & 63;
    const int g   = ln >> 4;
    const int r16 = ln & 15;
    const int bh = blockIdx.y;
    const int b = bh >> 4, h = bh & 15;
    const int s0 = blockIdx.x * 64;

    // Q fragments for this wave's 16 rows (B-operand layout: col=l&15, k=8g+j)
    bf16x8 qfrag[18];
    {
        const ushort_t* qp = qcat
            + ((long long)h * BS_ + (long long)b * S_ + (s0 + 16 * w + r16)) * 576 + 8 * g;
        #pragma unroll
        for (int kt = 0; kt < 18; ++kt)
            qfrag[kt] = *reinterpret_cast<const bf16x8*>(qp + 32 * kt);
    }

    const f32x4 zero4 = {0.f, 0.f, 0.f, 0.f};
    f32x4 acc[8][4];
    #pragma unroll
    for (int i = 0; i < 8; ++i)
        #pragma unroll
        for (int j = 0; j < 4; ++j) acc[i][j] = zero4;

    float m_run = -1e30f, l_run = 0.0f;
    const float scale = 0.0721687836487032f;  // 192^-0.5

    const ushort_t* kvsrc = kvb16 + (long long)b * S_ * 576;
    const ushort_t* vtsrc = vT16 + (long long)b * 512 * 2048;
    const int krow = tid >> 3, kseg = tid & 7;

    for (int t0 = 0; t0 < S_; t0 += 32) {
        __syncthreads();  // prev PV reads done
        // stage KV tile 32x576
        {
            const ushort_t* src = kvsrc + (long long)(t0 + krow) * 576 + kseg * 72;
            ushort_t* dst = &sKV[krow][kseg * 72];
            #pragma unroll
            for (int i = 0; i < 9; ++i)
                *reinterpret_cast<bf16x8*>(dst + 8 * i) =
                    *reinterpret_cast<const bf16x8*>(src + 8 * i);
        }
        // stage V^T tile 512x32 (swizzled)
        #pragma unroll
        for (int q = 0; q < 2; ++q) {
            int c = tid + 256 * q;
            const ushort_t* src = vtsrc + (long long)c * 2048 + t0;
            #pragma unroll
            for (int j = 0; j < 4; ++j) {
                int sw = ((c & 1) * 4 + j) ^ ((c >> 1) & 7);
                *reinterpret_cast<bf16x8*>(&sVT[(c >> 1) * 64 + sw * 8]) =
                    *reinterpret_cast<const bf16x8*>(src + 8 * j);
            }
        }
        __syncthreads();
        // scores^T: d0 = t-tile 0 (t=4g+reg), d1 = t-tile 1 (t=16+4g+reg); col = q-row r16
        f32x4 d0 = zero4, d1 = zero4;
        #pragma unroll
        for (int kt = 0; kt < 18; ++kt) {
            bf16x8 a0 = *reinterpret_cast<const bf16x8*>(&sKV[r16][kt * 32 + 8 * g]);
            bf16x8 a1 = *reinterpret_cast<const bf16x8*>(&sKV[16 + r16][kt * 32 + 8 * g]);
            d0 = __builtin_amdgcn_mfma_f32_16x16x32_bf16(a0, qfrag[kt], d0, 0, 0, 0);
            d1 = __builtin_amdgcn_mfma_f32_16x16x32_bf16(a1, qfrag[kt], d1, 0, 0, 0);
        }
        // lane-local online softmax (lane owns q-row 16w+r16; t spread over 4 lane groups)
        float p[8];
        #pragma unroll
        for (int i = 0; i < 4; ++i) { p[i] = d0[i] * scale; p[4 + i] = d1[i] * scale; }
        float mt = p[0];
        #pragma unroll
        for (int i = 1; i < 8; ++i) mt = fmaxf(mt, p[i]);
        mt = fmaxf(mt, __shfl_xor(mt, 16, 64));
        mt = fmaxf(mt, __shfl_xor(mt, 32, 64));
        bool anyneed = __any(mt > m_run + 8.0f);   // defer-max THR=8
        float m_new = anyneed ? fmaxf(m_run, mt) : m_run;
        float fac = anyneed ? __expf(m_run - m_new) : 1.0f;
        m_run = m_new;
        float lt = 0.f;
        #pragma unroll
        for (int i = 0; i < 8; ++i) { p[i] = __expf(p[i] - m_new); lt += p[i]; }
        lt += __shfl_xor(lt, 16, 64);
        lt += __shfl_xor(lt, 32, 64);
        l_run = l_run * fac + lt;
        // write P^T row (r = 16w+r16), fac, need-flag
        {
            int r = 16 * w + r16;
            uint_t* prow = reinterpret_cast<uint_t*>(&sP[r][0]);
            #pragma unroll
            for (int tt = 0; tt < 2; ++tt)
                #pragma unroll
                for (int pr = 0; pr < 2; ++pr) {
                    uint_t wrd = (uint_t)f2us(p[tt * 4 + 2 * pr])
                               | ((uint_t)f2us(p[tt * 4 + 2 * pr + 1]) << 16);
                    prow[tt * 8 + g * 2 + pr] = wrd;
                }
            if (g == 0) sFac[16 * w + r16] = fac;
            if (ln == 0) sNeedA[w] = anyneed ? 1 : 0;
        }
        __syncthreads();
        // PV: out^T[c][r] for c in [128w,128w+128), all 64 rows
        if (sNeedA[0] | sNeedA[1] | sNeedA[2] | sNeedA[3]) {
            float fv[4];
            #pragma unroll
            for (int nt = 0; nt < 4; ++nt) fv[nt] = sFac[16 * nt + r16];
            #pragma unroll
            for (int ct = 0; ct < 8; ++ct)
                #pragma unroll
                for (int nt = 0; nt < 4; ++nt) {
                    acc[ct][nt][0] *= fv[nt]; acc[ct][nt][1] *= fv[nt];
                    acc[ct][nt][2] *= fv[nt]; acc[ct][nt][3] *= fv[nt];
                }
        }
        bf16x8 pB[4];
        #pragma unroll
        for (int nt = 0; nt < 4; ++nt)
            pB[nt] = *reinterpret_cast<const bf16x8*>(&sP[16 * nt + r16][8 * g]);
        #pragma unroll
        for (int ct = 0; ct < 8; ++ct) {
            int c = 128 * w + 16 * ct + r16;
            int sw = ((c & 1) * 4 + g) ^ ((c >> 1) & 7);
            bf16x8 aV = *reinterpret_cast<const bf16x8*>(&sVT[(c >> 1) * 64 + sw * 8]);
            #pragma unroll
            for (int nt = 0; nt < 4; ++nt)
                acc[ct][nt] = __builtin_amdgcn_mfma_f32_16x16x32_bf16(aV, pB[nt], acc[ct][nt], 0, 0, 0);
        }
    }
    // finalize: l across rows, normalize, store out^T -> outc[bs][h][512]
    if (g == 0) sL[16 * w + r16] = l_run;
    __syncthreads();
    float inv[4];
    #pragma unroll
    for (int nt = 0; nt < 4; ++nt) inv[nt] = 1.0f / sL[16 * nt + r16];
    #pragma unroll
    for (int ct = 0; ct < 8; ++ct) {
        int cg = 128 * w + 16 * ct + 4 * g;
        #pragma unroll
        for (int nt = 0; nt < 4; ++nt) {
            long long row = (long long)b * S_ + s0 + 16 * nt + r16;
            ushort4 o;
            o.x = f2us(acc[ct][nt][0] * inv[nt]);
            o.y = f2us(acc[ct][nt][1] * inv[nt]);
            o.z = f2us(acc[ct][nt][2] * inv[nt]);
            o.w = f2us(acc[ct][nt][3] * inv[nt]);
            *reinterpret_cast<ushort4*>(outc + row * 8192 + h * 512 + cg) = o;
        }
    }
}

// ---------- workspace layout (bytes) ----------
// qbuf  f32 BS x 3072        @ 0           : 50,331,648   (dead after gemm5; aout overlaps @0)
// kvbuf f32 BS x 576         @ 50,331,648  :  9,437,184
// qcat  bf16 [H][BS][576]    @ 59,768,832  : 75,497,472
// kvb16 bf16 [BS][576]       @ 135,266,304 :  4,718,592
// vT16  bf16 [B][512][2048]  @ 139,984,896 :  4,194,304
// outc  bf16 [BS][H][512]    @ 144,179,200 : 67,108,864
// total 211,288,064

extern "C" void kernel_launch(void* const* d_in, const int* in_sizes, int n_in,
                              void* d_out, int out_size, void* d_ws, size_t ws_size,
                              hipStream_t stream)
{
    if (ws_size < 211288064ULL) return;
    const float* x    = (const float*)d_in[0];
    const float* fc   = (const float*)d_in[1];
    const float* fs   = (const float*)d_in[2];
    const float* wq   = (const float*)d_in[3];
    const float* wkva = (const float*)d_in[4];
    const float* wkvb = (const float*)d_in[5];
    const float* wo   = (const float*)d_in[6];
    float* out = (float*)d_out;

    char* ws = (char*)d_ws;
    float*    qbuf  = (float*)(ws);
    float*    aout  = (float*)(ws);                      // overlaps qbuf (dead by step 7)
    float*    kvbuf = (float*)(ws + 50331648);
    ushort_t* qcat  = (ushort_t*)(ws + 59768832);
    ushort_t* kvb16 = (ushort_t*)(ws + 135266304);
    ushort_t* vT16  = (ushort_t*)(ws + 139984896);
    ushort_t* outc  = (ushort_t*)(ws + 144179200);

    // 1) q = x @ wq^T  (4096x3072, K=2048) -> f32
    gemm_k<float, float, float, true><<<dim3(48, 64, 1), 256, 0, stream>>>(
        x, D_, 0, wq, D_, 0, qbuf, H_ * QK_, 0, BS_, H_ * QK_, D_);
    // 2) kv = x @ wkv_a^T (4096x576, K=2048) -> f32
    gemm_k<float, float, float, true><<<dim3(9, 64, 1), 256, 0, stream>>>(
        x, D_, 0, wkva, D_, 0, kvbuf, CR_, 0, BS_, CR_, D_);
    // 3) rope q_pe -> qcat pe-part (bf16)
    rope_q_k<<<dim3(BS_ * H_ * 32 / 256), 256, 0, stream>>>(qbuf, qcat, fc, fs);
    // 4) rmsnorm c + rope k_pe -> kvb16
    kvpost_k<<<dim3(BS_), 256, 0, stream>>>(kvbuf, kvb16, fc, fs);
    // 5) transpose -> vT16
    vtrans_k<<<dim3(S_ / 32, C_ / 32, B_), 256, 0, stream>>>(kvb16, vT16);
    // 6) q_abs[h] = q_nope[h] @ w_nope[h] -> qcat c-part (bf16, pitch 576)
    gemm_k<float, float, ushort_t, false><<<dim3(8, 64, 16), 256, 0, stream>>>(
        qbuf, H_ * QK_, QK_, wkvb, C_, (long long)(NOPE_ + V_) * C_,
        qcat, 576, (long long)BS_ * 576, BS_, C_, NOPE_);
    // 7) MFMA attention -> outc
    attn_mfma_k<<<dim3(S_ / 64, B_ * H_), 256, 0, stream>>>(qcat, kvb16, vT16, outc);
    // 8) out[h] = out_c[h] @ w_v[h]^T (z=16: 4096x128, K=512) -> aout f32
    gemm_k<ushort_t, float, float, true><<<dim3(2, 64, 16), 256, 0, stream>>>(
        outc, H_ * C_, C_, wkvb + (long long)NOPE_ * C_, C_, (long long)(NOPE_ + V_) * C_,
        aout, H_ * V_, V_, BS_, V_, C_);
    // 9) final = aout @ wo^T (4096x2048, K=2048) -> f32 out
    gemm_k<float, float, float, true><<<dim3(32, 64, 1), 256, 0, stream>>>(
        aout, H_ * V_, 0, wo, H_ * V_, 0, out, D_, 0, BS_, D_, H_ * V_);
}

// Round 4
// 879.214 us; speedup vs baseline: 12.8664x; 2.9087x over previous
//
#include <hip/hip_runtime.h>

#define B_ 2
#define S_ 2048
#define D_ 2048
#define H_ 16
#define NOPE_ 128
#define ROPE_ 64
#define V_ 128
#define C_ 512
#define QK_ 192   // NOPE+ROPE
#define CR_ 576   // C+ROPE
#define BS_ 4096  // B*S

typedef unsigned short ushort_t;
typedef unsigned int uint_t;
typedef __attribute__((ext_vector_type(8))) short bf16x8;
typedef __attribute__((ext_vector_type(4))) float f32x4;

// async global->LDS, 16B per lane. LDS dest = wave-uniform base + lane*16.
#define GLD16(gp, lp) __builtin_amdgcn_global_load_lds( \
    (const __attribute__((address_space(1))) void*)(gp), \
    (__attribute__((address_space(3))) void*)(lp), 16, 0, 0)

__device__ __forceinline__ float us2f(ushort_t u) {
    unsigned int x = ((unsigned int)u) << 16;
    return __uint_as_float(x);
}
__device__ __forceinline__ ushort_t f2us(float f) {
    unsigned int x = __float_as_uint(f);
    unsigned int r = (x + 0x7fffu + ((x >> 16) & 1u)) >> 16;
    return (ushort_t)r;
}

// ---------- f32 -> bf16 conversions ----------
__global__ __launch_bounds__(256) void conv_flat_k(
    const float* __restrict__ src, ushort_t* __restrict__ dst)
{
    long long i = ((long long)blockIdx.x * 256 + threadIdx.x) * 4;
    float4 v = *reinterpret_cast<const float4*>(src + i);
    ushort4 o; o.x = f2us(v.x); o.y = f2us(v.y); o.z = f2us(v.z); o.w = f2us(v.w);
    *reinterpret_cast<ushort4*>(dst + i) = o;
}

// wkva (576x2048) -> padded (640x2048), rows >=576 zero
__global__ __launch_bounds__(256) void conv_pad_k(
    const float* __restrict__ src, ushort_t* __restrict__ dst)
{
    long long i = ((long long)blockIdx.x * 256 + threadIdx.x) * 4;
    int row = (int)(i >> 11);
    ushort4 o;
    if (row < 576) {
        float4 v = *reinterpret_cast<const float4*>(src + i);
        o.x = f2us(v.x); o.y = f2us(v.y); o.z = f2us(v.z); o.w = f2us(v.w);
    } else { o.x = o.y = o.z = o.w = 0; }
    *reinterpret_cast<ushort4*>(dst + i) = o;
}

// w_nope (per h: rows 0..127 of 256x512) -> wnT [h][512][128] bf16 (transposed)
__global__ __launch_bounds__(256) void conv_wnt_k(
    const float* __restrict__ wkvb, ushort_t* __restrict__ wnT)
{
    __shared__ float st[32][33];
    int h = blockIdx.z;
    int d0 = blockIdx.x * 32, c0 = blockIdx.y * 32;
    int t = threadIdx.x;
    int dl = t >> 3, c4 = (t & 7) * 4;
    float4 v = *reinterpret_cast<const float4*>(
        wkvb + (long long)h * 131072 + (d0 + dl) * 512 + c0 + c4);
    st[dl][c4] = v.x; st[dl][c4+1] = v.y; st[dl][c4+2] = v.z; st[dl][c4+3] = v.w;
    __syncthreads();
    int cl = t >> 3, d4 = (t & 7) * 4;
    ushort4 o;
    o.x = f2us(st[d4][cl]);   o.y = f2us(st[d4+1][cl]);
    o.z = f2us(st[d4+2][cl]); o.w = f2us(st[d4+3][cl]);
    *reinterpret_cast<ushort4*>(wnT + (long long)h * 65536 + (c0 + cl) * 128 + d0 + d4) = o;
}

// w_v (per h: rows 128..255 of 256x512) -> wvb [h][128][512] bf16
__global__ __launch_bounds__(256) void conv_wv_k(
    const float* __restrict__ wkvb, ushort_t* __restrict__ wvb)
{
    long long i = ((long long)blockIdx.x * 256 + threadIdx.x) * 4;  // 0..1048575
    int h = (int)(i >> 16);
    int rem = (int)(i & 65535);
    float4 v = *reinterpret_cast<const float4*>(wkvb + (long long)h * 131072 + 65536 + rem);
    ushort4 o; o.x = f2us(v.x); o.y = f2us(v.y); o.z = f2us(v.z); o.w = f2us(v.w);
    *reinterpret_cast<ushort4*>(wvb + i) = o;
}

// ---------- MFMA GEMM: C[M][N] = A[M][K] * B^T (B stored N x K), bf16 in ----------
// 128x128 tile, BK=32, 256 threads (4 waves 2x2), global_load_lds staging (m97 structure).
template <typename TC, bool NGUARD>
__global__ __launch_bounds__(256) void gemm_mfma_k(
    const ushort_t* __restrict__ A, int lda, long long strideAz,
    const ushort_t* __restrict__ Bm, int ldb, long long strideBz,
    TC* __restrict__ Cm, int ldc, long long strideCz,
    int K, int N_real)
{
    __shared__ ushort_t sA[128 * 32];
    __shared__ ushort_t sB[128 * 32];
    const int tid = threadIdx.x;
    const int w = tid >> 6, ln = tid & 63;
    const int g = ln >> 4, r16 = ln & 15;
    const int wr = w >> 1, wc = w & 1;
    const int z = blockIdx.z;
    A  += (long long)z * strideAz;
    Bm += (long long)z * strideBz;
    Cm += (long long)z * strideCz;
    const long long m0 = (long long)blockIdx.y * 128;
    const long long n0 = (long long)blockIdx.x * 128;

    // staging: chunk p = q*256+tid (q=0,1): row=p>>2 (0..127), kc=p&3
    const int r0 = tid >> 2, kc8 = (tid & 3) * 8;
    const ushort_t* a0 = A + (m0 + r0) * lda + kc8;
    const ushort_t* a1 = A + (m0 + 64 + r0) * lda + kc8;
    const ushort_t* b0 = Bm + (n0 + r0) * ldb + kc8;
    const ushort_t* b1 = Bm + (n0 + 64 + r0) * ldb + kc8;
    ushort_t* sA0 = sA + w * 512;          // wave-uniform LDS bases
    ushort_t* sA1 = sA + 2048 + w * 512;
    ushort_t* sB0 = sB + w * 512;
    ushort_t* sB1 = sB + 2048 + w * 512;

    const f32x4 zero4 = {0.f, 0.f, 0.f, 0.f};
    f32x4 acc[4][4];
    #pragma unroll
    for (int i = 0; i < 4; ++i)
        #pragma unroll
        for (int j = 0; j < 4; ++j) acc[i][j] = zero4;

    for (int k0 = 0; k0 < K; k0 += 32) {
        GLD16(a0 + k0, sA0);
        GLD16(a1 + k0, sA1);
        GLD16(b0 + k0, sB0);
        GLD16(b1 + k0, sB1);
        __syncthreads();
        bf16x8 af[4], bfr[4];
        #pragma unroll
        for (int i = 0; i < 4; ++i)
            af[i] = *reinterpret_cast<const bf16x8*>(&sA[(64 * wr + 16 * i + r16) * 32 + 8 * g]);
        #pragma unroll
        for (int j = 0; j < 4; ++j)
            bfr[j] = *reinterpret_cast<const bf16x8*>(&sB[(64 * wc + 16 * j + r16) * 32 + 8 * g]);
        __builtin_amdgcn_s_setprio(1);
        #pragma unroll
        for (int i = 0; i < 4; ++i)
            #pragma unroll
            for (int j = 0; j < 4; ++j)
                acc[i][j] = __builtin_amdgcn_mfma_f32_16x16x32_bf16(af[i], bfr[j], acc[i][j], 0, 0, 0);
        __builtin_amdgcn_s_setprio(0);
        __syncthreads();
    }
    // C store: D row = 4g+r within 16-block of A rows, col = r16 within B cols
    #pragma unroll
    for (int i = 0; i < 4; ++i) {
        #pragma unroll
        for (int j = 0; j < 4; ++j) {
            int nn = (int)n0 + 64 * wc + 16 * j + r16;
            if (NGUARD && nn >= N_real) continue;
            #pragma unroll
            for (int r = 0; r < 4; ++r) {
                long long row = m0 + 64 * wr + 16 * i + 4 * g + r;
                float v = acc[i][j][r];
                if constexpr (sizeof(TC) == 2) Cm[row * ldc + nn] = (TC)f2us(v);
                else                           Cm[row * ldc + nn] = (TC)v;
            }
        }
    }
}

// ---------- RoPE on q_pe: read qb16, write qcat pe-part ----------
__global__ __launch_bounds__(256) void rope_q_k(
    const ushort_t* __restrict__ qb, ushort_t* __restrict__ qcat,
    const float* __restrict__ fc, const float* __restrict__ fs)
{
    int id = blockIdx.x * 256 + threadIdx.x;           // BS*H*32 total
    int i  = id & 31;
    int h  = (id >> 5) & 15;
    int bs = id >> 9;
    int s  = bs & (S_ - 1);
    float c  = fc[s * 32 + i];
    float sn = fs[s * 32 + i];
    uint_t w2 = *reinterpret_cast<const uint_t*>(
        qb + (long long)bs * 3072 + h * QK_ + NOPE_ + 2 * i);
    float tr = us2f((ushort_t)(w2 & 0xffffu));
    float ti = us2f((ushort_t)(w2 >> 16));
    float orr = tr * c - ti * sn;
    float oii = tr * sn + ti * c;
    uint_t wrd = (uint_t)f2us(orr) | ((uint_t)f2us(oii) << 16);
    ((uint_t*)qcat)[((long long)h * BS_ + bs) * 288 + 256 + i] = wrd;
}

// ---------- kv post: rmsnorm(c) + rope(k_pe) -> kvb16 bf16 [BS][576] ----------
__global__ __launch_bounds__(256) void kvpost_k(
    const float* __restrict__ kv, ushort_t* __restrict__ kvb16,
    const float* __restrict__ fc, const float* __restrict__ fs)
{
    int bs = blockIdx.x;
    const float* row = kv + (long long)bs * CR_;
    ushort_t* orow = kvb16 + (long long)bs * CR_;
    int tid = threadIdx.x;
    float v0 = row[tid], v1 = row[tid + 256];
    float ss = v0 * v0 + v1 * v1;
    #pragma unroll
    for (int m = 1; m < 64; m <<= 1) ss += __shfl_xor(ss, m, 64);
    __shared__ float red[4];
    if ((tid & 63) == 0) red[tid >> 6] = ss;
    __syncthreads();
    float tot = red[0] + red[1] + red[2] + red[3];
    float r = rsqrtf(tot * (1.0f / (float)C_) + 1e-6f);
    orow[tid] = f2us(v0 * r);
    orow[tid + 256] = f2us(v1 * r);
    if (tid < 32) {
        int s = bs & (S_ - 1);
        float c  = fc[s * 32 + tid];
        float sn = fs[s * 32 + tid];
        float tr = row[C_ + 2 * tid], ti = row[C_ + 2 * tid + 1];
        orow[C_ + 2 * tid]     = f2us(tr * c - ti * sn);
        orow[C_ + 2 * tid + 1] = f2us(tr * sn + ti * c);
    }
}

// ---------- transpose c-part of kvb16 -> vT16 [B][512][2048] ----------
__global__ __launch_bounds__(256) void vtrans_k(
    const ushort_t* __restrict__ kvb16, ushort_t* __restrict__ vT16)
{
    __shared__ ushort_t st[32][36];
    int b = blockIdx.z;
    int s0 = blockIdx.x * 32, c0 = blockIdx.y * 32;
    int t = threadIdx.x;
    int sl = t >> 3, c4 = (t & 7) * 4;
    ushort4 v = *reinterpret_cast<const ushort4*>(
        kvb16 + ((long long)(b * S_ + s0 + sl)) * CR_ + c0 + c4);
    st[sl][c4] = v.x; st[sl][c4+1] = v.y; st[sl][c4+2] = v.z; st[sl][c4+3] = v.w;
    __syncthreads();
    int cl = t >> 3, s4 = (t & 7) * 4;
    ushort4 o;
    o.x = st[s4][cl]; o.y = st[s4+1][cl]; o.z = st[s4+2][cl]; o.w = st[s4+3][cl];
    *reinterpret_cast<ushort4*>(
        vT16 + ((long long)b * 512 + c0 + cl) * 2048 + s0 + s4) = o;
}

// ---------- MFMA flash attention (gload_lds staging + swizzles) ----------
__global__ __launch_bounds__(256, 2) void attn_mfma_k(
    const ushort_t* __restrict__ qcat,   // [H][BS][576] bf16
    const ushort_t* __restrict__ kvb16,  // [BS][576] bf16
    const ushort_t* __restrict__ vT16,   // [B][512][2048] bf16
    ushort_t* __restrict__ outc)         // [BS][H*512] bf16
{
    __shared__ ushort_t sKV[32 * 576];   // XOR-swizzled: chunk c_st holds logical c_st^(row&7) (low3)
    __shared__ ushort_t sVT[512 * 32];   // line-pair chunk-XOR swizzle
    __shared__ ushort_t sP[64][40];
    __shared__ float sFac[64];
    __shared__ float sL[64];
    __shared__ int sNeedA[4];

    const int tid = threadIdx.x;
    const int w   = tid >> 6;
    const int ln  = tid & 63;
    const int g   = ln >> 4;
    const int r16 = ln & 15;
    const int bh = blockIdx.y;
    const int b = bh >> 4, h = bh & 15;
    const int s0 = blockIdx.x * 64;

    // precompute per-lane staging source offsets (inverse-swizzled)
    int kvoff[9];
    #pragma unroll
    for (int i = 0; i < 9; ++i) {
        int p = i * 256 + tid;          // 16B-chunk index, 0..2303
        int row = p / 72, cs = p - row * 72;
        int clog = (cs & ~7) | ((cs ^ row) & 7);
        kvoff[i] = row * 576 + clog * 8;
    }
    int vtoff[8];
    #pragma unroll
    for (int i = 0; i < 8; ++i) {
        int p = i * 256 + tid;          // 0..2047
        int rp = p >> 3, sw = p & 7;
        int lg = sw ^ (rp & 7);
        vtoff[i] = (2 * rp + (lg >> 2)) * 2048 + (lg & 3) * 8;
    }

    // Q fragments (B-operand: col=l&15=q-row, k=8g+j)
    bf16x8 qfrag[18];
    {
        const ushort_t* qp = qcat
            + ((long long)h * BS_ + (long long)b * S_ + (s0 + 16 * w + r16)) * 576 + 8 * g;
        #pragma unroll
        for (int kt = 0; kt < 18; ++kt)
            qfrag[kt] = *reinterpret_cast<const bf16x8*>(qp + 32 * kt);
    }

    const f32x4 zero4 = {0.f, 0.f, 0.f, 0.f};
    f32x4 acc[8][4];
    #pragma unroll
    for (int i = 0; i < 8; ++i)
        #pragma unroll
        for (int j = 0; j < 4; ++j) acc[i][j] = zero4;

    float m_run = -1e30f, l_run = 0.0f;
    const float scale = 0.0721687836487032f;  // 192^-0.5

    const ushort_t* kvsrc = kvb16 + (long long)b * S_ * 576;
    const ushort_t* vtsrc = vT16 + (long long)b * 512 * 2048;
    char* skvb = (char*)sKV;
    char* svtb = (char*)sVT;

    for (int t0 = 0; t0 < S_; t0 += 32) {
        __syncthreads();  // prev tile reads done
        {
            const ushort_t* kvt = kvsrc + (long long)t0 * 576;
            const ushort_t* vtt = vtsrc + t0;
            #pragma unroll
            for (int i = 0; i < 9; ++i)
                GLD16(kvt + kvoff[i], skvb + i * 4096 + w * 1024);
            #pragma unroll
            for (int i = 0; i < 8; ++i)
                GLD16(vtt + vtoff[i], svtb + i * 4096 + w * 1024);
        }
        __syncthreads();
        // scores^T = mfma(A=KV rows, B=Q): lane holds q-row r16, t = 4g+reg (+16 for d1)
        f32x4 d0 = zero4, d1 = zero4;
        __builtin_amdgcn_s_setprio(1);
        #pragma unroll
        for (int kt = 0; kt < 18; ++kt) {
            int ch = kt * 4 + g;
            int chs = (ch & ~7) | ((ch ^ r16) & 7);
            bf16x8 a0 = *reinterpret_cast<const bf16x8*>(&sKV[r16 * 576 + chs * 8]);
            bf16x8 a1 = *reinterpret_cast<const bf16x8*>(&sKV[(16 + r16) * 576 + chs * 8]);
            d0 = __builtin_amdgcn_mfma_f32_16x16x32_bf16(a0, qfrag[kt], d0, 0, 0, 0);
            d1 = __builtin_amdgcn_mfma_f32_16x16x32_bf16(a1, qfrag[kt], d1, 0, 0, 0);
        }
        __builtin_amdgcn_s_setprio(0);
        // lane-local online softmax
        float p[8];
        #pragma unroll
        for (int i = 0; i < 4; ++i) { p[i] = d0[i] * scale; p[4 + i] = d1[i] * scale; }
        float mt = p[0];
        #pragma unroll
        for (int i = 1; i < 8; ++i) mt = fmaxf(mt, p[i]);
        mt = fmaxf(mt, __shfl_xor(mt, 16, 64));
        mt = fmaxf(mt, __shfl_xor(mt, 32, 64));
        bool anyneed = __any(mt > m_run + 8.0f);   // defer-max THR=8
        float m_new = anyneed ? fmaxf(m_run, mt) : m_run;
        float fac = anyneed ? __expf(m_run - m_new) : 1.0f;
        m_run = m_new;
        float lt = 0.f;
        #pragma unroll
        for (int i = 0; i < 8; ++i) { p[i] = __expf(p[i] - m_new); lt += p[i]; }
        lt += __shfl_xor(lt, 16, 64);
        lt += __shfl_xor(lt, 32, 64);
        l_run = l_run * fac + lt;
        {
            int r = 16 * w + r16;
            uint_t* prow = reinterpret_cast<uint_t*>(&sP[r][0]);
            #pragma unroll
            for (int tt = 0; tt < 2; ++tt)
                #pragma unroll
                for (int pr = 0; pr < 2; ++pr) {
                    uint_t wrd = (uint_t)f2us(p[tt * 4 + 2 * pr])
                               | ((uint_t)f2us(p[tt * 4 + 2 * pr + 1]) << 16);
                    prow[tt * 8 + g * 2 + pr] = wrd;
                }
            if (g == 0) sFac[16 * w + r16] = fac;
            if (ln == 0) sNeedA[w] = anyneed ? 1 : 0;
        }
        __syncthreads();
        // PV: out^T = mfma(A=V^T rows, B=P^T)
        if (sNeedA[0] | sNeedA[1] | sNeedA[2] | sNeedA[3]) {
            float fv[4];
            #pragma unroll
            for (int nt = 0; nt < 4; ++nt) fv[nt] = sFac[16 * nt + r16];
            #pragma unroll
            for (int ct = 0; ct < 8; ++ct)
                #pragma unroll
                for (int nt = 0; nt < 4; ++nt) {
                    acc[ct][nt][0] *= fv[nt]; acc[ct][nt][1] *= fv[nt];
                    acc[ct][nt][2] *= fv[nt]; acc[ct][nt][3] *= fv[nt];
                }
        }
        bf16x8 pB[4];
        #pragma unroll
        for (int nt = 0; nt < 4; ++nt)
            pB[nt] = *reinterpret_cast<const bf16x8*>(&sP[16 * nt + r16][8 * g]);
        __builtin_amdgcn_s_setprio(1);
        #pragma unroll
        for (int ct = 0; ct < 8; ++ct) {
            int c = 128 * w + 16 * ct + r16;
            int sw = ((c & 1) * 4 + g) ^ ((c >> 1) & 7);
            bf16x8 aV = *reinterpret_cast<const bf16x8*>(&sVT[(c >> 1) * 64 + sw * 8]);
            #pragma unroll
            for (int nt = 0; nt < 4; ++nt)
                acc[ct][nt] = __builtin_amdgcn_mfma_f32_16x16x32_bf16(aV, pB[nt], acc[ct][nt], 0, 0, 0);
        }
        __builtin_amdgcn_s_setprio(0);
    }
    if (g == 0) sL[16 * w + r16] = l_run;
    __syncthreads();
    float inv[4];
    #pragma unroll
    for (int nt = 0; nt < 4; ++nt) inv[nt] = 1.0f / sL[16 * nt + r16];
    #pragma unroll
    for (int ct = 0; ct < 8; ++ct) {
        int cg = 128 * w + 16 * ct + 4 * g;
        #pragma unroll
        for (int nt = 0; nt < 4; ++nt) {
            long long row = (long long)b * S_ + s0 + 16 * nt + r16;
            ushort4 o;
            o.x = f2us(acc[ct][nt][0] * inv[nt]);
            o.y = f2us(acc[ct][nt][1] * inv[nt]);
            o.z = f2us(acc[ct][nt][2] * inv[nt]);
            o.w = f2us(acc[ct][nt][3] * inv[nt]);
            *reinterpret_cast<ushort4*>(outc + row * 8192 + h * 512 + cg) = o;
        }
    }
}

// ---------- workspace layout (bytes), total 221,773,824 ----------
// qcat   @ 0           75,497,472
// outc   @ 75,497,472  67,108,864
// qb16   @ 142,606,336 25,165,824
// xb     @ 167,772,160 16,777,216   (aoutb aliases: xb dead after gemm2)
// wqb    @ 184,549,376 12,582,912   (kvb16 @184,549,376 / vT16 @189,267,968 alias: wqb dead after gemm1)
// kvbuf  @ 197,132,288  9,437,184
// wob    @ 206,569,472  8,388,608
// wkvab  @ 214,958,080  2,621,440
// wnTb   @ 217,579,520  2,097,152
// wvb    @ 219,676,672  2,097,152

extern "C" void kernel_launch(void* const* d_in, const int* in_sizes, int n_in,
                              void* d_out, int out_size, void* d_ws, size_t ws_size,
                              hipStream_t stream)
{
    if (ws_size < 221773824ULL) return;
    const float* x    = (const float*)d_in[0];
    const float* fc   = (const float*)d_in[1];
    const float* fs   = (const float*)d_in[2];
    const float* wq   = (const float*)d_in[3];
    const float* wkva = (const float*)d_in[4];
    const float* wkvb = (const float*)d_in[5];
    const float* wo   = (const float*)d_in[6];
    float* out = (float*)d_out;

    char* ws = (char*)d_ws;
    ushort_t* qcat  = (ushort_t*)(ws);
    ushort_t* outc  = (ushort_t*)(ws + 75497472);
    ushort_t* qb16  = (ushort_t*)(ws + 142606336);
    ushort_t* xb    = (ushort_t*)(ws + 167772160);
    ushort_t* aoutb = (ushort_t*)(ws + 167772160);   // alias xb
    ushort_t* wqb   = (ushort_t*)(ws + 184549376);
    ushort_t* kvb16 = (ushort_t*)(ws + 184549376);   // alias wqb
    ushort_t* vT16  = (ushort_t*)(ws + 189267968);   // alias wqb tail
    float*    kvbuf = (float*)(ws + 197132288);
    ushort_t* wob   = (ushort_t*)(ws + 206569472);
    ushort_t* wkvab = (ushort_t*)(ws + 214958080);
    ushort_t* wnTb  = (ushort_t*)(ws + 217579520);
    ushort_t* wvb   = (ushort_t*)(ws + 219676672);

    // 0) conversions
    conv_flat_k<<<dim3(8192), 256, 0, stream>>>(x, xb);            // 8.4M elems
    conv_flat_k<<<dim3(6144), 256, 0, stream>>>(wq, wqb);          // 6.3M
    conv_flat_k<<<dim3(4096), 256, 0, stream>>>(wo, wob);          // 4.2M
    conv_pad_k<<<dim3(1280), 256, 0, stream>>>(wkva, wkvab);       // 640x2048
    conv_wnt_k<<<dim3(4, 16, 16), 256, 0, stream>>>(wkvb, wnTb);
    conv_wv_k<<<dim3(1024), 256, 0, stream>>>(wkvb, wvb);
    // 1) q = x @ wq^T -> qb16 bf16 [BS][3072]
    gemm_mfma_k<ushort_t, false><<<dim3(24, 32, 1), 256, 0, stream>>>(
        xb, D_, 0, wqb, D_, 0, qb16, 3072, 0, D_, 3072);
    // 2) kv = x @ wkv_a^T -> kvbuf f32 [BS][576] (B padded to 640)
    gemm_mfma_k<float, true><<<dim3(5, 32, 1), 256, 0, stream>>>(
        xb, D_, 0, wkvab, D_, 0, kvbuf, CR_, 0, D_, CR_);
    // 3) rope q_pe -> qcat pe-part
    rope_q_k<<<dim3(BS_ * H_ * 32 / 256), 256, 0, stream>>>(qb16, qcat, fc, fs);
    // 4) rmsnorm c + rope k_pe -> kvb16
    kvpost_k<<<dim3(BS_), 256, 0, stream>>>(kvbuf, kvb16, fc, fs);
    // 5) transpose -> vT16
    vtrans_k<<<dim3(S_ / 32, C_ / 32, B_), 256, 0, stream>>>(kvb16, vT16);
    // 6) q_abs[h] = q_nope[h] @ wnT[h]^T -> qcat c-part (z=16)
    gemm_mfma_k<ushort_t, false><<<dim3(4, 32, 16), 256, 0, stream>>>(
        qb16, 3072, 192, wnTb, 128, 65536, qcat, 576, (long long)BS_ * 576, NOPE_, 512);
    // 7) MFMA attention -> outc
    attn_mfma_k<<<dim3(S_ / 64, B_ * H_), 256, 0, stream>>>(qcat, kvb16, vT16, outc);
    // 8) out_v[h] = out_c[h] @ w_v[h]^T -> aoutb bf16 (z=16)
    gemm_mfma_k<ushort_t, false><<<dim3(1, 32, 16), 256, 0, stream>>>(
        outc, 8192, 512, wvb, 512, 65536, aoutb, 2048, 128, C_, 128);
    // 9) final = aout @ wo^T -> f32 out
    gemm_mfma_k<float, false><<<dim3(16, 32, 1), 256, 0, stream>>>(
        aoutb, 2048, 0, wob, 2048, 0, out, D_, 0, 2048, 2048);
}